// Round 1
// baseline (10953.930 us; speedup 1.0000x reference)
//
#include <hip/hip_runtime.h>

#define NN 200000
#define EE 3200000
#define HID 32

// ---------------- degree / norm prep ----------------

__global__ void k_deg(const int* __restrict__ ei, float* __restrict__ deg) {
    int e = blockIdx.x * 256 + threadIdx.x;
    if (e < EE) {
        unsafeAtomicAdd(&deg[ei[e]], 1.0f);   // deg over src
    }
}

__global__ void k_dinv(float* deg) {
    int i = blockIdx.x * 256 + threadIdx.x;
    if (i < NN) {
        float d = deg[i];
        deg[i] = d > 0.f ? rsqrtf(d) : 0.f;
    }
}

__global__ void k_prep(const int* __restrict__ ei, const float* __restrict__ dinv,
                       int* __restrict__ sidx, int* __restrict__ didx,
                       float* __restrict__ nw) {
    int e = blockIdx.x * 256 + threadIdx.x;
    if (e < EE) {
        int s = ei[e];
        int d = ei[EE + e];
        sidx[e] = s;
        didx[e] = d;
        nw[e] = -dinv[s] * dinv[d];
    }
}

// ---------------- input MLP: h = relu(x @ W0 + b0) ----------------

__global__ void k_mlp0(const float* __restrict__ x, const float* __restrict__ W0,
                       const float* __restrict__ b0, float* __restrict__ out) {
    int t = blockIdx.x * 256 + threadIdx.x;   // t = n*32 + o
    int n = t >> 5, o = t & 31;
    if (n < NN) {
        float acc = b0[o];
#pragma unroll
        for (int i = 0; i < 3; i++) acc += x[n * 3 + i] * W0[i * 32 + o];
        out[t] = fmaxf(acc, 0.f);
    }
}

// ---------------- propagation: y[dst] += nw * x[src] ----------------
// 8 threads per edge, float4 per thread (one 128B node row per edge).

__global__ void k_prop(const int* __restrict__ sidx, const int* __restrict__ didx,
                       const float* __restrict__ nw, const float* __restrict__ x,
                       float* __restrict__ y) {
    int t = blockIdx.x * 256 + threadIdx.x;
    int e = t >> 3, c = t & 7;
    if (e < EE) {
        int s = sidx[e], d = didx[e];
        float w = nw[e];
        float4 v = *reinterpret_cast<const float4*>(x + s * 32 + c * 4);
        float* yp = y + d * 32 + c * 4;
        unsafeAtomicAdd(yp + 0, w * v.x);
        unsafeAtomicAdd(yp + 1, w * v.y);
        unsafeAtomicAdd(yp + 2, w * v.z);
        unsafeAtomicAdd(yp + 3, w * v.w);
    }
}

// ---------------- fused Cheb combine ----------------
// out = [relu]( T0@W[0] + P1@W[1] + (2*P2 - T0)@W[2] + b [+ res] )
// LDS-stages the 4 input rows so out may alias res / inputs safely.

__global__ void k_cheb(const float* T0, const float* P1, const float* P2,
                       const float* res, float* out,
                       const float* __restrict__ W, const float* __restrict__ b,
                       int do_relu, int has_res) {
    __shared__ float sT0[8][32], sP1[8][32], sP2[8][32], sR[8][32];
    int t = threadIdx.x;           // t = nl*32 + o
    int nl = t >> 5, o = t & 31;
    int gi = blockIdx.x * 256 + t; // node n = gi/32
    sT0[nl][o] = T0[gi];
    sP1[nl][o] = P1[gi];
    sP2[nl][o] = P2[gi];
    sR[nl][o] = has_res ? res[gi] : 0.f;
    __syncthreads();
    float acc = b[o] + sR[nl][o];
#pragma unroll
    for (int i = 0; i < 32; i++) {
        float w0 = W[i * 32 + o];
        float w1 = W[1024 + i * 32 + o];
        float w2 = W[2048 + i * 32 + o];
        float t0 = sT0[nl][i];
        acc += t0 * w0 + sP1[nl][i] * w1 + (2.f * sP2[nl][i] - t0) * w2;
    }
    if (do_relu) acc = fmaxf(acc, 0.f);
    out[gi] = acc;
}

// ---------------- final head: out = X @ W1 + b1 ----------------

__global__ void k_final(const float* __restrict__ X, const float* __restrict__ W1,
                        const float* __restrict__ b1, float* __restrict__ out) {
    int n = blockIdx.x * 256 + threadIdx.x;
    if (n < NN) {
        float acc = b1[0];
        const float4* xp = reinterpret_cast<const float4*>(X + n * 32);
#pragma unroll
        for (int c = 0; c < 8; c++) {
            float4 v = xp[c];
            acc += v.x * W1[c * 4 + 0] + v.y * W1[c * 4 + 1] +
                   v.z * W1[c * 4 + 2] + v.w * W1[c * 4 + 3];
        }
        out[n] = acc;
    }
}

extern "C" void kernel_launch(void* const* d_in, const int* in_sizes, int n_in,
                              void* d_out, int out_size, void* d_ws, size_t ws_size,
                              hipStream_t stream) {
    const float* x    = (const float*)d_in[0];
    const int*   ei   = (const int*)d_in[1];
    const float* W0   = (const float*)d_in[2];
    const float* b0   = (const float*)d_in[3];
    const float* c11W = (const float*)d_in[4];
    const float* c11b = (const float*)d_in[5];
    const float* c12W = (const float*)d_in[6];
    const float* c12b = (const float*)d_in[7];
    const float* c21W = (const float*)d_in[8];
    const float* c21b = (const float*)d_in[9];
    const float* c22W = (const float*)d_in[10];
    const float* c22b = (const float*)d_in[11];
    const float* W1   = (const float*)d_in[12];
    const float* b1   = (const float*)d_in[13];
    float* out = (float*)d_out;

    char* ws = (char*)d_ws;
    float* deg = (float*)ws; ws += (size_t)NN * 4;
    int*  sidx = (int*)ws;   ws += (size_t)EE * 4;
    int*  didx = (int*)ws;   ws += (size_t)EE * 4;
    float* nw  = (float*)ws; ws += (size_t)EE * 4;
    float* F0  = (float*)ws; ws += (size_t)NN * HID * 4;
    float* F1  = (float*)ws; ws += (size_t)NN * HID * 4;
    float* P1  = (float*)ws; ws += (size_t)NN * HID * 4;
    float* P2  = (float*)ws; ws += (size_t)NN * HID * 4;

    const size_t featB = (size_t)NN * HID * 4;

    hipMemsetAsync(deg, 0, (size_t)NN * 4, stream);
    k_deg<<<(EE + 255) / 256, 256, 0, stream>>>(ei, deg);
    k_dinv<<<(NN + 255) / 256, 256, 0, stream>>>(deg);
    k_prep<<<(EE + 255) / 256, 256, 0, stream>>>(ei, deg, sidx, didx, nw);
    k_mlp0<<<NN * HID / 256, 256, 0, stream>>>(x, W0, b0, F0);

    auto conv = [&](const float* T0, const float* res, float* outb,
                    const float* W, const float* b, int relu, int has_res) {
        hipMemsetAsync(P1, 0, featB, stream);
        k_prop<<<EE * 8 / 256, 256, 0, stream>>>(sidx, didx, nw, T0, P1);
        hipMemsetAsync(P2, 0, featB, stream);
        k_prop<<<EE * 8 / 256, 256, 0, stream>>>(sidx, didx, nw, P1, P2);
        k_cheb<<<NN / 8, 256, 0, stream>>>(T0, P1, P2, res, outb, W, b, relu, has_res);
    };

    conv(F0, nullptr, F1, c11W, c11b, 1, 0);   // block1 conv1: relu
    conv(F1, F0,      F0, c12W, c12b, 1, 1);   // block1 conv2: +res, relu
    conv(F0, nullptr, F1, c21W, c21b, 1, 0);   // block2 conv1: relu
    conv(F1, F0,      F0, c22W, c22b, 1, 1);   // block2 conv2: +res, relu

    k_final<<<(NN + 255) / 256, 256, 0, stream>>>(F0, W1, b1, out);
}

// Round 3
// 1752.380 us; speedup vs baseline: 6.2509x; 6.2509x over previous
//
#include <hip/hip_runtime.h>

#define NN 200000
#define EE 3200000
#define HID 32
#define NB 196   // ceil(NN/1024) scan blocks

// ---------------- histogram: deg over src (for norm) and dst (for CSR) -------

__global__ void k_deg(const int* __restrict__ ei, int* __restrict__ dsrc,
                      int* __restrict__ ddst) {
    int e = blockIdx.x * 256 + threadIdx.x;
    if (e < EE) {
        atomicAdd(&dsrc[ei[e]], 1);
        atomicAdd(&ddst[ei[EE + e]], 1);
    }
}

__global__ void k_dinv(const int* __restrict__ dsrc, float* __restrict__ dinv) {
    int i = blockIdx.x * 256 + threadIdx.x;
    if (i < NN) {
        int d = dsrc[i];
        dinv[i] = d > 0 ? rsqrtf((float)d) : 0.f;
    }
}

// ---------------- exclusive scan of ddst -> rowptr (3-phase) ----------------

__global__ void k_scan1(const int* __restrict__ deg, int* __restrict__ pre,
                        int* __restrict__ bsum) {
    __shared__ int s[256];
    int tid = threadIdx.x;
    int base = blockIdx.x * 1024 + tid * 4;
    int v0 = (base + 0 < NN) ? deg[base + 0] : 0;
    int v1 = (base + 1 < NN) ? deg[base + 1] : 0;
    int v2 = (base + 2 < NN) ? deg[base + 2] : 0;
    int v3 = (base + 3 < NN) ? deg[base + 3] : 0;
    int tsum = v0 + v1 + v2 + v3;
    s[tid] = tsum;
    __syncthreads();
    for (int off = 1; off < 256; off <<= 1) {
        int t = (tid >= off) ? s[tid - off] : 0;
        __syncthreads();
        s[tid] += t;
        __syncthreads();
    }
    int excl = s[tid] - tsum;
    if (tid == 255) bsum[blockIdx.x] = s[255];
    if (base + 0 < NN) pre[base + 0] = excl;
    if (base + 1 < NN) pre[base + 1] = excl + v0;
    if (base + 2 < NN) pre[base + 2] = excl + v0 + v1;
    if (base + 3 < NN) pre[base + 3] = excl + v0 + v1 + v2;
}

__global__ void k_scan2(const int* __restrict__ bsum, int* __restrict__ boff) {
    __shared__ int s[256];
    int tid = threadIdx.x;
    int v = (tid < NB) ? bsum[tid] : 0;
    s[tid] = v;
    __syncthreads();
    for (int off = 1; off < 256; off <<= 1) {
        int t = (tid >= off) ? s[tid - off] : 0;
        __syncthreads();
        s[tid] += t;
        __syncthreads();
    }
    if (tid < NB) boff[tid] = s[tid] - v;
}

__global__ void k_scan3(int* __restrict__ rowptr, const int* __restrict__ boff) {
    int base = blockIdx.x * 1024 + threadIdx.x * 4;
    int o = boff[blockIdx.x];
#pragma unroll
    for (int k = 0; k < 4; k++)
        if (base + k < NN) rowptr[base + k] += o;
    if (blockIdx.x == 0 && threadIdx.x == 0) rowptr[NN] = EE;
}

// ---------------- CSR fill: csr[pos] = (src, -dinv[s]*dinv[d]) --------------

__global__ void k_fill(const int* __restrict__ ei, const float* __restrict__ dinv,
                       const int* __restrict__ rowptr, int* __restrict__ cnt,
                       int2* __restrict__ csr) {
    int e = blockIdx.x * 256 + threadIdx.x;
    if (e < EE) {
        int s = ei[e];
        int d = ei[EE + e];
        float w = -dinv[s] * dinv[d];
        int pos = rowptr[d] + atomicAdd(&cnt[d], 1);
        csr[pos] = make_int2(s, __float_as_int(w));
    }
}

// ---------------- input MLP: h = relu(x @ W0 + b0) ----------------

__global__ void k_mlp0(const float* __restrict__ x, const float* __restrict__ W0,
                       const float* __restrict__ b0, float* __restrict__ out) {
    int t = blockIdx.x * 256 + threadIdx.x;   // t = n*32 + o
    int n = t >> 5, o = t & 31;
    if (n < NN) {
        float acc = b0[o];
#pragma unroll
        for (int i = 0; i < 3; i++) acc += x[n * 3 + i] * W0[i * 32 + o];
        out[t] = fmaxf(acc, 0.f);
    }
}

// ---------------- propagation (CSR, gather-only, no atomics) ----------------
// 8 threads per node, float4 per thread; register accumulate; coalesced write.

__global__ void k_prop_csr(const int* __restrict__ rowptr, const int2* __restrict__ csr,
                           const float* __restrict__ x, float* __restrict__ y) {
    int t = blockIdx.x * 256 + threadIdx.x;
    int n = t >> 3, c = t & 7;
    if (n >= NN) return;
    int beg = rowptr[n], end = rowptr[n + 1];
    float4 acc = make_float4(0.f, 0.f, 0.f, 0.f);
    for (int j = beg; j < end; j++) {
        int2 e = csr[j];
        float w = __int_as_float(e.y);
        float4 v = *reinterpret_cast<const float4*>(x + (size_t)e.x * 32 + c * 4);
        acc.x += w * v.x;
        acc.y += w * v.y;
        acc.z += w * v.z;
        acc.w += w * v.w;
    }
    *reinterpret_cast<float4*>(y + (size_t)n * 32 + c * 4) = acc;
}

// ---------------- fused Cheb combine ----------------
// out = relu?( T0@W[0] + P1@W[1] + (2*P2 - T0)@W[2] + b [+ res] )

__global__ void k_cheb(const float* T0, const float* P1, const float* P2,
                       const float* res, float* out,
                       const float* __restrict__ W, const float* __restrict__ b,
                       int do_relu, int has_res) {
    __shared__ float sT0[8][32], sP1[8][32], sP2[8][32], sR[8][32];
    int t = threadIdx.x;           // t = nl*32 + o
    int nl = t >> 5, o = t & 31;
    int gi = blockIdx.x * 256 + t;
    sT0[nl][o] = T0[gi];
    sP1[nl][o] = P1[gi];
    sP2[nl][o] = P2[gi];
    sR[nl][o] = has_res ? res[gi] : 0.f;
    __syncthreads();
    float acc = b[o] + sR[nl][o];
#pragma unroll
    for (int i = 0; i < 32; i++) {
        float w0 = W[i * 32 + o];
        float w1 = W[1024 + i * 32 + o];
        float w2 = W[2048 + i * 32 + o];
        float t0 = sT0[nl][i];
        acc += t0 * w0 + sP1[nl][i] * w1 + (2.f * sP2[nl][i] - t0) * w2;
    }
    if (do_relu) acc = fmaxf(acc, 0.f);
    out[gi] = acc;
}

// ---------------- final head: out = X @ W1 + b1 ----------------

__global__ void k_final(const float* __restrict__ X, const float* __restrict__ W1,
                        const float* __restrict__ b1, float* __restrict__ out) {
    int n = blockIdx.x * 256 + threadIdx.x;
    if (n < NN) {
        float acc = b1[0];
        const float4* xp = reinterpret_cast<const float4*>(X + n * 32);
#pragma unroll
        for (int c = 0; c < 8; c++) {
            float4 v = xp[c];
            acc += v.x * W1[c * 4 + 0] + v.y * W1[c * 4 + 1] +
                   v.z * W1[c * 4 + 2] + v.w * W1[c * 4 + 3];
        }
        out[n] = acc;
    }
}

extern "C" void kernel_launch(void* const* d_in, const int* in_sizes, int n_in,
                              void* d_out, int out_size, void* d_ws, size_t ws_size,
                              hipStream_t stream) {
    const float* x    = (const float*)d_in[0];
    const int*   ei   = (const int*)d_in[1];
    const float* W0   = (const float*)d_in[2];
    const float* b0   = (const float*)d_in[3];
    const float* c11W = (const float*)d_in[4];
    const float* c11b = (const float*)d_in[5];
    const float* c12W = (const float*)d_in[6];
    const float* c12b = (const float*)d_in[7];
    const float* c21W = (const float*)d_in[8];
    const float* c21b = (const float*)d_in[9];
    const float* c22W = (const float*)d_in[10];
    const float* c22b = (const float*)d_in[11];
    const float* W1   = (const float*)d_in[12];
    const float* b1   = (const float*)d_in[13];
    float* out = (float*)d_out;

    char* ws = (char*)d_ws;
    // zeroed region (one memset): dsrc, ddst, cnt
    int* dsrc = (int*)ws;    ws += (size_t)NN * 4;
    int* ddst = (int*)ws;    ws += (size_t)NN * 4;
    int* cnt  = (int*)ws;    ws += (size_t)NN * 4;
    float* dinv = (float*)ws; ws += (size_t)NN * 4;
    int* rowptr = (int*)ws;  ws += (size_t)(NN + 1) * 4;
    int* bsum  = (int*)ws;   ws += 256 * 4;
    int* boff  = (int*)ws;   ws += 256 * 4;
    int2* csr  = (int2*)(((uintptr_t)ws + 15) & ~(uintptr_t)15); ws = (char*)csr + (size_t)EE * 8;
    float* F0  = (float*)ws; ws += (size_t)NN * HID * 4;
    float* F1  = (float*)ws; ws += (size_t)NN * HID * 4;
    float* P1  = (float*)ws; ws += (size_t)NN * HID * 4;
    float* P2  = (float*)ws; ws += (size_t)NN * HID * 4;

    hipMemsetAsync(dsrc, 0, (size_t)NN * 3 * 4, stream);

    k_deg<<<(EE + 255) / 256, 256, 0, stream>>>(ei, dsrc, ddst);
    k_dinv<<<(NN + 255) / 256, 256, 0, stream>>>(dsrc, dinv);
    k_scan1<<<NB, 256, 0, stream>>>(ddst, rowptr, bsum);
    k_scan2<<<1, 256, 0, stream>>>(bsum, boff);
    k_scan3<<<NB, 256, 0, stream>>>(rowptr, boff);
    k_fill<<<(EE + 255) / 256, 256, 0, stream>>>(ei, dinv, rowptr, cnt, csr);

    k_mlp0<<<NN * HID / 256, 256, 0, stream>>>(x, W0, b0, F0);

    auto conv = [&](const float* T0, const float* res, float* outb,
                    const float* W, const float* b, int relu, int has_res) {
        k_prop_csr<<<NN * 8 / 256, 256, 0, stream>>>(rowptr, csr, T0, P1);
        k_prop_csr<<<NN * 8 / 256, 256, 0, stream>>>(rowptr, csr, P1, P2);
        k_cheb<<<NN / 8, 256, 0, stream>>>(T0, P1, P2, res, outb, W, b, relu, has_res);
    };

    conv(F0, nullptr, F1, c11W, c11b, 1, 0);   // block1 conv1: relu
    conv(F1, F0,      F0, c12W, c12b, 1, 1);   // block1 conv2: +res, relu
    conv(F0, nullptr, F1, c21W, c21b, 1, 0);   // block2 conv1: relu
    conv(F1, F0,      F0, c22W, c22b, 1, 1);   // block2 conv2: +res, relu

    k_final<<<(NN + 255) / 256, 256, 0, stream>>>(F0, W1, b1, out);
}

// Round 4
// 1594.411 us; speedup vs baseline: 6.8702x; 1.0991x over previous
//
#include <hip/hip_runtime.h>

#define NN 200000
#define EE 3200000
#define HID 32
#define NB 196    // ceil(NN/1024) scan blocks
#define HB 16384  // histogram bins per group (64 KB LDS)
#define HG 13     // bin groups: 13*16384 = 212992 >= NN
#define HBK 25    // edge slices; EE/HBK = 128000 exactly
#define ESL (EE / HBK)

// ---------------- two-level histogram (no device atomics) ----------------
// grid = HG*HBK blocks; block (b,g) histograms slice b over bin range g.

__global__ __launch_bounds__(256) void k_hist(const int* __restrict__ vals,
                                              int* __restrict__ partial) {
    __shared__ int h[HB];
    int b = blockIdx.x / HG, g = blockIdx.x % HG;   // same-slice blocks adjacent
    int base = g * HB;
    for (int i = threadIdx.x; i < HB; i += 256) h[i] = 0;
    __syncthreads();
    const int4* p4 = reinterpret_cast<const int4*>(vals + (size_t)b * ESL);
    for (int i = threadIdx.x; i < ESL / 4; i += 256) {
        int4 v = p4[i];
        int a0 = v.x - base, a1 = v.y - base, a2 = v.z - base, a3 = v.w - base;
        if ((unsigned)a0 < HB) atomicAdd(&h[a0], 1);
        if ((unsigned)a1 < HB) atomicAdd(&h[a1], 1);
        if ((unsigned)a2 < HB) atomicAdd(&h[a2], 1);
        if ((unsigned)a3 < HB) atomicAdd(&h[a3], 1);
    }
    __syncthreads();
    int* out = partial + ((size_t)g * HBK + b) * HB;
    for (int i = threadIdx.x; i < HB; i += 256) out[i] = h[i];
}

__global__ void k_hreduce(const int* __restrict__ partial, int* __restrict__ out) {
    int bi = blockIdx.x * 256 + threadIdx.x;
    if (bi >= NN) return;
    int g = bi >> 14, i = bi & (HB - 1);
    const int* p = partial + (size_t)g * HBK * HB + i;
    int s = 0;
#pragma unroll
    for (int b = 0; b < HBK; b++) s += p[(size_t)b << 14];
    out[bi] = s;
}

__global__ void k_dinv(const int* __restrict__ dsrc, float* __restrict__ dinv) {
    int i = blockIdx.x * 256 + threadIdx.x;
    if (i < NN) {
        int d = dsrc[i];
        dinv[i] = d > 0 ? rsqrtf((float)d) : 0.f;
    }
}

// ---------------- exclusive scan of ddst -> rowptr (3-phase) ----------------

__global__ void k_scan1(const int* __restrict__ deg, int* __restrict__ pre,
                        int* __restrict__ bsum) {
    __shared__ int s[256];
    int tid = threadIdx.x;
    int base = blockIdx.x * 1024 + tid * 4;
    int v0 = (base + 0 < NN) ? deg[base + 0] : 0;
    int v1 = (base + 1 < NN) ? deg[base + 1] : 0;
    int v2 = (base + 2 < NN) ? deg[base + 2] : 0;
    int v3 = (base + 3 < NN) ? deg[base + 3] : 0;
    int tsum = v0 + v1 + v2 + v3;
    s[tid] = tsum;
    __syncthreads();
    for (int off = 1; off < 256; off <<= 1) {
        int t = (tid >= off) ? s[tid - off] : 0;
        __syncthreads();
        s[tid] += t;
        __syncthreads();
    }
    int excl = s[tid] - tsum;
    if (tid == 255) bsum[blockIdx.x] = s[255];
    if (base + 0 < NN) pre[base + 0] = excl;
    if (base + 1 < NN) pre[base + 1] = excl + v0;
    if (base + 2 < NN) pre[base + 2] = excl + v0 + v1;
    if (base + 3 < NN) pre[base + 3] = excl + v0 + v1 + v2;
}

__global__ void k_scan2(const int* __restrict__ bsum, int* __restrict__ boff) {
    __shared__ int s[256];
    int tid = threadIdx.x;
    int v = (tid < NB) ? bsum[tid] : 0;
    s[tid] = v;
    __syncthreads();
    for (int off = 1; off < 256; off <<= 1) {
        int t = (tid >= off) ? s[tid - off] : 0;
        __syncthreads();
        s[tid] += t;
        __syncthreads();
    }
    if (tid < NB) boff[tid] = s[tid] - v;
}

__global__ void k_scan3(int* __restrict__ rowptr, const int* __restrict__ boff) {
    int base = blockIdx.x * 1024 + threadIdx.x * 4;
    int o = boff[blockIdx.x];
#pragma unroll
    for (int k = 0; k < 4; k++)
        if (base + k < NN) rowptr[base + k] += o;
    if (blockIdx.x == 0 && threadIdx.x == 0) rowptr[NN] = EE;
}

// ---------------- CSR fill: csr[pos] = (src, -dinv[s]*dinv[d]) --------------

__global__ void k_fill(const int* __restrict__ ei, const float* __restrict__ dinv,
                       const int* __restrict__ rowptr, int* __restrict__ cnt,
                       int2* __restrict__ csr) {
    int e = blockIdx.x * 256 + threadIdx.x;
    if (e < EE) {
        int s = ei[e];
        int d = ei[EE + e];
        float w = -dinv[s] * dinv[d];
        int pos = rowptr[d] + atomicAdd(&cnt[d], 1);
        csr[pos] = make_int2(s, __float_as_int(w));
    }
}

// ---------------- input MLP: h = relu(x @ W0 + b0) ----------------

__global__ void k_mlp0(const float* __restrict__ x, const float* __restrict__ W0,
                       const float* __restrict__ b0, float* __restrict__ out) {
    int t = blockIdx.x * 256 + threadIdx.x;   // t = n*32 + o
    int n = t >> 5, o = t & 31;
    if (n < NN) {
        float acc = b0[o];
#pragma unroll
        for (int i = 0; i < 3; i++) acc += x[n * 3 + i] * W0[i * 32 + o];
        out[t] = fmaxf(acc, 0.f);
    }
}

// ---------------- propagation (CSR, gather-only, unrolled for MLP) ----------
// 8 threads/node, float4 per thread; 8/4-wide batches of independent gathers.

__global__ __launch_bounds__(256) void k_prop_csr(const int* __restrict__ rowptr,
                                                  const int2* __restrict__ csr,
                                                  const float* __restrict__ x,
                                                  float* __restrict__ y) {
    int t = blockIdx.x * 256 + threadIdx.x;
    int n = t >> 3, c = t & 7;
    if (n >= NN) return;
    int beg = rowptr[n], end = rowptr[n + 1];
    float4 acc = make_float4(0.f, 0.f, 0.f, 0.f);
    int j = beg;
    const float* xc = x + (size_t)c * 4;
    for (; j + 8 <= end; j += 8) {
        int2 e0 = csr[j + 0], e1 = csr[j + 1], e2 = csr[j + 2], e3 = csr[j + 3];
        int2 e4 = csr[j + 4], e5 = csr[j + 5], e6 = csr[j + 6], e7 = csr[j + 7];
        float4 v0 = *(const float4*)(xc + (size_t)e0.x * 32);
        float4 v1 = *(const float4*)(xc + (size_t)e1.x * 32);
        float4 v2 = *(const float4*)(xc + (size_t)e2.x * 32);
        float4 v3 = *(const float4*)(xc + (size_t)e3.x * 32);
        float4 v4 = *(const float4*)(xc + (size_t)e4.x * 32);
        float4 v5 = *(const float4*)(xc + (size_t)e5.x * 32);
        float4 v6 = *(const float4*)(xc + (size_t)e6.x * 32);
        float4 v7 = *(const float4*)(xc + (size_t)e7.x * 32);
        float w0 = __int_as_float(e0.y), w1 = __int_as_float(e1.y);
        float w2 = __int_as_float(e2.y), w3 = __int_as_float(e3.y);
        float w4 = __int_as_float(e4.y), w5 = __int_as_float(e5.y);
        float w6 = __int_as_float(e6.y), w7 = __int_as_float(e7.y);
        acc.x += w0 * v0.x + w1 * v1.x + w2 * v2.x + w3 * v3.x
               + w4 * v4.x + w5 * v5.x + w6 * v6.x + w7 * v7.x;
        acc.y += w0 * v0.y + w1 * v1.y + w2 * v2.y + w3 * v3.y
               + w4 * v4.y + w5 * v5.y + w6 * v6.y + w7 * v7.y;
        acc.z += w0 * v0.z + w1 * v1.z + w2 * v2.z + w3 * v3.z
               + w4 * v4.z + w5 * v5.z + w6 * v6.z + w7 * v7.z;
        acc.w += w0 * v0.w + w1 * v1.w + w2 * v2.w + w3 * v3.w
               + w4 * v4.w + w5 * v5.w + w6 * v6.w + w7 * v7.w;
    }
    for (; j + 4 <= end; j += 4) {
        int2 e0 = csr[j + 0], e1 = csr[j + 1], e2 = csr[j + 2], e3 = csr[j + 3];
        float4 v0 = *(const float4*)(xc + (size_t)e0.x * 32);
        float4 v1 = *(const float4*)(xc + (size_t)e1.x * 32);
        float4 v2 = *(const float4*)(xc + (size_t)e2.x * 32);
        float4 v3 = *(const float4*)(xc + (size_t)e3.x * 32);
        float w0 = __int_as_float(e0.y), w1 = __int_as_float(e1.y);
        float w2 = __int_as_float(e2.y), w3 = __int_as_float(e3.y);
        acc.x += w0 * v0.x + w1 * v1.x + w2 * v2.x + w3 * v3.x;
        acc.y += w0 * v0.y + w1 * v1.y + w2 * v2.y + w3 * v3.y;
        acc.z += w0 * v0.z + w1 * v1.z + w2 * v2.z + w3 * v3.z;
        acc.w += w0 * v0.w + w1 * v1.w + w2 * v2.w + w3 * v3.w;
    }
    for (; j < end; j++) {
        int2 e = csr[j];
        float w = __int_as_float(e.y);
        float4 v = *(const float4*)(xc + (size_t)e.x * 32);
        acc.x += w * v.x; acc.y += w * v.y; acc.z += w * v.z; acc.w += w * v.w;
    }
    *reinterpret_cast<float4*>(y + (size_t)n * 32 + c * 4) = acc;
}

// ---------------- fused Cheb combine ----------------
// out = relu?( T0@W[0] + P1@W[1] + (2*P2 - T0)@W[2] + b [+ res] )

__global__ void k_cheb(const float* T0, const float* P1, const float* P2,
                       const float* res, float* out,
                       const float* __restrict__ W, const float* __restrict__ b,
                       int do_relu, int has_res) {
    __shared__ float sT0[8][32], sP1[8][32], sP2[8][32], sR[8][32];
    int t = threadIdx.x;           // t = nl*32 + o
    int nl = t >> 5, o = t & 31;
    int gi = blockIdx.x * 256 + t;
    sT0[nl][o] = T0[gi];
    sP1[nl][o] = P1[gi];
    sP2[nl][o] = P2[gi];
    sR[nl][o] = has_res ? res[gi] : 0.f;
    __syncthreads();
    float acc = b[o] + sR[nl][o];
#pragma unroll
    for (int i = 0; i < 32; i++) {
        float w0 = W[i * 32 + o];
        float w1 = W[1024 + i * 32 + o];
        float w2 = W[2048 + i * 32 + o];
        float t0 = sT0[nl][i];
        acc += t0 * w0 + sP1[nl][i] * w1 + (2.f * sP2[nl][i] - t0) * w2;
    }
    if (do_relu) acc = fmaxf(acc, 0.f);
    out[gi] = acc;
}

// ---------------- final head: out = X @ W1 + b1 ----------------

__global__ void k_final(const float* __restrict__ X, const float* __restrict__ W1,
                        const float* __restrict__ b1, float* __restrict__ out) {
    int n = blockIdx.x * 256 + threadIdx.x;
    if (n < NN) {
        float acc = b1[0];
        const float4* xp = reinterpret_cast<const float4*>(X + n * 32);
#pragma unroll
        for (int c = 0; c < 8; c++) {
            float4 v = xp[c];
            acc += v.x * W1[c * 4 + 0] + v.y * W1[c * 4 + 1] +
                   v.z * W1[c * 4 + 2] + v.w * W1[c * 4 + 3];
        }
        out[n] = acc;
    }
}

extern "C" void kernel_launch(void* const* d_in, const int* in_sizes, int n_in,
                              void* d_out, int out_size, void* d_ws, size_t ws_size,
                              hipStream_t stream) {
    const float* x    = (const float*)d_in[0];
    const int*   ei   = (const int*)d_in[1];
    const float* W0   = (const float*)d_in[2];
    const float* b0   = (const float*)d_in[3];
    const float* c11W = (const float*)d_in[4];
    const float* c11b = (const float*)d_in[5];
    const float* c12W = (const float*)d_in[6];
    const float* c12b = (const float*)d_in[7];
    const float* c21W = (const float*)d_in[8];
    const float* c21b = (const float*)d_in[9];
    const float* c22W = (const float*)d_in[10];
    const float* c22b = (const float*)d_in[11];
    const float* W1   = (const float*)d_in[12];
    const float* b1   = (const float*)d_in[13];
    float* out = (float*)d_out;

    char* ws = (char*)d_ws;
    int* dsrc = (int*)ws;    ws += (size_t)NN * 4;
    int* ddst = (int*)ws;    ws += (size_t)NN * 4;
    int* cnt  = (int*)ws;    ws += (size_t)NN * 4;   // memset target
    float* dinv = (float*)ws; ws += (size_t)NN * 4;
    int* rowptr = (int*)ws;  ws += (size_t)(NN + 1) * 4;
    int* bsum  = (int*)ws;   ws += 256 * 4;
    int* boff  = (int*)ws;   ws += 256 * 4;
    int2* csr  = (int2*)(((uintptr_t)ws + 15) & ~(uintptr_t)15); ws = (char*)csr + (size_t)EE * 8;
    float* F0  = (float*)ws; ws += (size_t)NN * HID * 4;
    float* F1  = (float*)ws; ws += (size_t)NN * HID * 4;
    float* P1  = (float*)ws; ws += (size_t)NN * HID * 4;
    float* P2  = (float*)ws; ws += (size_t)NN * HID * 4;
    // histogram partials alias P1 (21.3 MB <= 25.6 MB; consumed before first prop)
    int* partial = (int*)P1;

    hipMemsetAsync(cnt, 0, (size_t)NN * 4, stream);

    k_hist<<<HG * HBK, 256, 0, stream>>>(ei, partial);                 // src degrees
    k_hreduce<<<(NN + 255) / 256, 256, 0, stream>>>(partial, dsrc);
    k_hist<<<HG * HBK, 256, 0, stream>>>(ei + EE, partial);            // dst degrees
    k_hreduce<<<(NN + 255) / 256, 256, 0, stream>>>(partial, ddst);
    k_dinv<<<(NN + 255) / 256, 256, 0, stream>>>(dsrc, dinv);
    k_scan1<<<NB, 256, 0, stream>>>(ddst, rowptr, bsum);
    k_scan2<<<1, 256, 0, stream>>>(bsum, boff);
    k_scan3<<<NB, 256, 0, stream>>>(rowptr, boff);
    k_fill<<<(EE + 255) / 256, 256, 0, stream>>>(ei, dinv, rowptr, cnt, csr);

    k_mlp0<<<NN * HID / 256, 256, 0, stream>>>(x, W0, b0, F0);

    auto conv = [&](const float* T0, const float* res, float* outb,
                    const float* W, const float* b, int relu, int has_res) {
        k_prop_csr<<<NN * 8 / 256, 256, 0, stream>>>(rowptr, csr, T0, P1);
        k_prop_csr<<<NN * 8 / 256, 256, 0, stream>>>(rowptr, csr, P1, P2);
        k_cheb<<<NN / 8, 256, 0, stream>>>(T0, P1, P2, res, outb, W, b, relu, has_res);
    };

    conv(F0, nullptr, F1, c11W, c11b, 1, 0);   // block1 conv1: relu
    conv(F1, F0,      F0, c12W, c12b, 1, 1);   // block1 conv2: +res, relu
    conv(F0, nullptr, F1, c21W, c21b, 1, 0);   // block2 conv1: relu
    conv(F1, F0,      F0, c22W, c22b, 1, 1);   // block2 conv2: +res, relu

    k_final<<<(NN + 255) / 256, 256, 0, stream>>>(F0, W1, b1, out);
}

// Round 5
// 1278.728 us; speedup vs baseline: 8.5663x; 1.2469x over previous
//
#include <hip/hip_runtime.h>
#include <hip/hip_fp16.h>

#define NN 200000
#define EE 3200000
#define HID 32
#define NB 196    // ceil(NN/1024) scan blocks
#define HB 16384  // histogram bins per group (64 KB LDS)
#define HG 13     // bin groups: 13*16384 = 212992 >= NN
#define HBK 25    // edge slices; EE/HBK = 128000 exactly
#define ESL (EE / HBK)

// ---------------- fp16 pack helpers (4 halfs <-> float4, 8B memory op) ------

__device__ inline float4 ld_h4(const __half* p) {
    uint2 u = *reinterpret_cast<const uint2*>(p);
    __half2 a = *reinterpret_cast<__half2*>(&u.x);
    __half2 b = *reinterpret_cast<__half2*>(&u.y);
    float2 fa = __half22float2(a), fb = __half22float2(b);
    return make_float4(fa.x, fa.y, fb.x, fb.y);
}

__device__ inline void st_h4(__half* p, float4 v) {
    __half2 a = __floats2half2_rn(v.x, v.y);
    __half2 b = __floats2half2_rn(v.z, v.w);
    uint2 u;
    u.x = *reinterpret_cast<unsigned*>(&a);
    u.y = *reinterpret_cast<unsigned*>(&b);
    *reinterpret_cast<uint2*>(p) = u;
}

// ---------------- two-level histogram (no device atomics) ----------------

__global__ __launch_bounds__(256) void k_hist(const int* __restrict__ vals,
                                              int* __restrict__ partial) {
    __shared__ int h[HB];
    int b = blockIdx.x / HG, g = blockIdx.x % HG;   // same-slice blocks adjacent
    int base = g * HB;
    for (int i = threadIdx.x; i < HB; i += 256) h[i] = 0;
    __syncthreads();
    const int4* p4 = reinterpret_cast<const int4*>(vals + (size_t)b * ESL);
    for (int i = threadIdx.x; i < ESL / 4; i += 256) {
        int4 v = p4[i];
        int a0 = v.x - base, a1 = v.y - base, a2 = v.z - base, a3 = v.w - base;
        if ((unsigned)a0 < HB) atomicAdd(&h[a0], 1);
        if ((unsigned)a1 < HB) atomicAdd(&h[a1], 1);
        if ((unsigned)a2 < HB) atomicAdd(&h[a2], 1);
        if ((unsigned)a3 < HB) atomicAdd(&h[a3], 1);
    }
    __syncthreads();
    int* out = partial + ((size_t)g * HBK + b) * HB;
    for (int i = threadIdx.x; i < HB; i += 256) out[i] = h[i];
}

__global__ void k_hreduce(const int* __restrict__ partial, int* __restrict__ out) {
    int bi = blockIdx.x * 256 + threadIdx.x;
    if (bi >= NN) return;
    int g = bi >> 14, i = bi & (HB - 1);
    const int* p = partial + (size_t)g * HBK * HB + i;
    int s = 0;
#pragma unroll
    for (int b = 0; b < HBK; b++) s += p[(size_t)b << 14];
    out[bi] = s;
}

__global__ void k_dinv(const int* __restrict__ dsrc, float* __restrict__ dinv) {
    int i = blockIdx.x * 256 + threadIdx.x;
    if (i < NN) {
        int d = dsrc[i];
        dinv[i] = d > 0 ? rsqrtf((float)d) : 0.f;
    }
}

// ---------------- exclusive scan of ddst -> rowptr (3-phase) ----------------

__global__ void k_scan1(const int* __restrict__ deg, int* __restrict__ pre,
                        int* __restrict__ bsum) {
    __shared__ int s[256];
    int tid = threadIdx.x;
    int base = blockIdx.x * 1024 + tid * 4;
    int v0 = (base + 0 < NN) ? deg[base + 0] : 0;
    int v1 = (base + 1 < NN) ? deg[base + 1] : 0;
    int v2 = (base + 2 < NN) ? deg[base + 2] : 0;
    int v3 = (base + 3 < NN) ? deg[base + 3] : 0;
    int tsum = v0 + v1 + v2 + v3;
    s[tid] = tsum;
    __syncthreads();
    for (int off = 1; off < 256; off <<= 1) {
        int t = (tid >= off) ? s[tid - off] : 0;
        __syncthreads();
        s[tid] += t;
        __syncthreads();
    }
    int excl = s[tid] - tsum;
    if (tid == 255) bsum[blockIdx.x] = s[255];
    if (base + 0 < NN) pre[base + 0] = excl;
    if (base + 1 < NN) pre[base + 1] = excl + v0;
    if (base + 2 < NN) pre[base + 2] = excl + v0 + v1;
    if (base + 3 < NN) pre[base + 3] = excl + v0 + v1 + v2;
}

__global__ void k_scan2(const int* __restrict__ bsum, int* __restrict__ boff) {
    __shared__ int s[256];
    int tid = threadIdx.x;
    int v = (tid < NB) ? bsum[tid] : 0;
    s[tid] = v;
    __syncthreads();
    for (int off = 1; off < 256; off <<= 1) {
        int t = (tid >= off) ? s[tid - off] : 0;
        __syncthreads();
        s[tid] += t;
        __syncthreads();
    }
    if (tid < NB) boff[tid] = s[tid] - v;
}

__global__ void k_scan3(int* __restrict__ rowptr, const int* __restrict__ boff) {
    int base = blockIdx.x * 1024 + threadIdx.x * 4;
    int o = boff[blockIdx.x];
#pragma unroll
    for (int k = 0; k < 4; k++)
        if (base + k < NN) rowptr[base + k] += o;
    if (blockIdx.x == 0 && threadIdx.x == 0) rowptr[NN] = EE;
}

// ---------------- CSR fill: csr[pos] = (src, -dinv[s]*dinv[d]) --------------

__global__ void k_fill(const int* __restrict__ ei, const float* __restrict__ dinv,
                       const int* __restrict__ rowptr, int* __restrict__ cnt,
                       int2* __restrict__ csr) {
    int e = blockIdx.x * 256 + threadIdx.x;
    if (e < EE) {
        int s = ei[e];
        int d = ei[EE + e];
        float w = -dinv[s] * dinv[d];
        int pos = rowptr[d] + atomicAdd(&cnt[d], 1);
        csr[pos] = make_int2(s, __float_as_int(w));
    }
}

// ---------------- input MLP: h = relu(x @ W0 + b0), fp16 out ----------------

__global__ void k_mlp0(const float* __restrict__ x, const float* __restrict__ W0,
                       const float* __restrict__ b0, __half* __restrict__ out) {
    int t = blockIdx.x * 256 + threadIdx.x;   // t = n*32 + o
    int n = t >> 5, o = t & 31;
    if (n < NN) {
        float acc = b0[o];
#pragma unroll
        for (int i = 0; i < 3; i++) acc += x[n * 3 + i] * W0[i * 32 + o];
        out[t] = __float2half(fmaxf(acc, 0.f));
    }
}

// ---------------- propagation (CSR, gather-only, fp16 features) -------------
// 8 threads/node, 4 halfs (8B) per thread => 1 cache line per edge row.

__global__ __launch_bounds__(256) void k_prop_csr(const int* __restrict__ rowptr,
                                                  const int2* __restrict__ csr,
                                                  const __half* __restrict__ x,
                                                  __half* __restrict__ y) {
    int t = blockIdx.x * 256 + threadIdx.x;
    int n = t >> 3, c = t & 7;
    if (n >= NN) return;
    int beg = rowptr[n], end = rowptr[n + 1];
    float4 acc = make_float4(0.f, 0.f, 0.f, 0.f);
    int j = beg;
    const __half* xc = x + (size_t)c * 4;
    for (; j + 8 <= end; j += 8) {
        int2 e0 = csr[j + 0], e1 = csr[j + 1], e2 = csr[j + 2], e3 = csr[j + 3];
        int2 e4 = csr[j + 4], e5 = csr[j + 5], e6 = csr[j + 6], e7 = csr[j + 7];
        float4 v0 = ld_h4(xc + (size_t)e0.x * 32);
        float4 v1 = ld_h4(xc + (size_t)e1.x * 32);
        float4 v2 = ld_h4(xc + (size_t)e2.x * 32);
        float4 v3 = ld_h4(xc + (size_t)e3.x * 32);
        float4 v4 = ld_h4(xc + (size_t)e4.x * 32);
        float4 v5 = ld_h4(xc + (size_t)e5.x * 32);
        float4 v6 = ld_h4(xc + (size_t)e6.x * 32);
        float4 v7 = ld_h4(xc + (size_t)e7.x * 32);
        float w0 = __int_as_float(e0.y), w1 = __int_as_float(e1.y);
        float w2 = __int_as_float(e2.y), w3 = __int_as_float(e3.y);
        float w4 = __int_as_float(e4.y), w5 = __int_as_float(e5.y);
        float w6 = __int_as_float(e6.y), w7 = __int_as_float(e7.y);
        acc.x += w0 * v0.x + w1 * v1.x + w2 * v2.x + w3 * v3.x
               + w4 * v4.x + w5 * v5.x + w6 * v6.x + w7 * v7.x;
        acc.y += w0 * v0.y + w1 * v1.y + w2 * v2.y + w3 * v3.y
               + w4 * v4.y + w5 * v5.y + w6 * v6.y + w7 * v7.y;
        acc.z += w0 * v0.z + w1 * v1.z + w2 * v2.z + w3 * v3.z
               + w4 * v4.z + w5 * v5.z + w6 * v6.z + w7 * v7.z;
        acc.w += w0 * v0.w + w1 * v1.w + w2 * v2.w + w3 * v3.w
               + w4 * v4.w + w5 * v5.w + w6 * v6.w + w7 * v7.w;
    }
    for (; j + 4 <= end; j += 4) {
        int2 e0 = csr[j + 0], e1 = csr[j + 1], e2 = csr[j + 2], e3 = csr[j + 3];
        float4 v0 = ld_h4(xc + (size_t)e0.x * 32);
        float4 v1 = ld_h4(xc + (size_t)e1.x * 32);
        float4 v2 = ld_h4(xc + (size_t)e2.x * 32);
        float4 v3 = ld_h4(xc + (size_t)e3.x * 32);
        float w0 = __int_as_float(e0.y), w1 = __int_as_float(e1.y);
        float w2 = __int_as_float(e2.y), w3 = __int_as_float(e3.y);
        acc.x += w0 * v0.x + w1 * v1.x + w2 * v2.x + w3 * v3.x;
        acc.y += w0 * v0.y + w1 * v1.y + w2 * v2.y + w3 * v3.y;
        acc.z += w0 * v0.z + w1 * v1.z + w2 * v2.z + w3 * v3.z;
        acc.w += w0 * v0.w + w1 * v1.w + w2 * v2.w + w3 * v3.w;
    }
    for (; j < end; j++) {
        int2 e = csr[j];
        float w = __int_as_float(e.y);
        float4 v = ld_h4(xc + (size_t)e.x * 32);
        acc.x += w * v.x; acc.y += w * v.y; acc.z += w * v.z; acc.w += w * v.w;
    }
    st_h4(y + (size_t)n * 32 + c * 4, acc);
}

// ---------------- fused Cheb combine (fp16 I/O, fp32 math) ----------------
// out = relu?( T0@W[0] + P1@W[1] + (2*P2 - T0)@W[2] + b [+ res] )

__global__ void k_cheb(const __half* T0, const __half* P1, const __half* P2,
                       const __half* res, __half* out,
                       const float* __restrict__ W, const float* __restrict__ b,
                       int do_relu, int has_res) {
    __shared__ float sT0[8][32], sP1[8][32], sP2[8][32], sR[8][32];
    int t = threadIdx.x;           // t = nl*32 + o
    int nl = t >> 5, o = t & 31;
    int gi = blockIdx.x * 256 + t;
    sT0[nl][o] = __half2float(T0[gi]);
    sP1[nl][o] = __half2float(P1[gi]);
    sP2[nl][o] = __half2float(P2[gi]);
    sR[nl][o] = has_res ? __half2float(res[gi]) : 0.f;
    __syncthreads();
    float acc = b[o] + sR[nl][o];
#pragma unroll
    for (int i = 0; i < 32; i++) {
        float w0 = W[i * 32 + o];
        float w1 = W[1024 + i * 32 + o];
        float w2 = W[2048 + i * 32 + o];
        float t0 = sT0[nl][i];
        acc += t0 * w0 + sP1[nl][i] * w1 + (2.f * sP2[nl][i] - t0) * w2;
    }
    if (do_relu) acc = fmaxf(acc, 0.f);
    out[gi] = __float2half(acc);
}

// ---------------- final head: out = X @ W1 + b1 (fp16 in, fp32 out) ---------

__global__ void k_final(const __half* __restrict__ X, const float* __restrict__ W1,
                        const float* __restrict__ b1, float* __restrict__ out) {
    int n = blockIdx.x * 256 + threadIdx.x;
    if (n < NN) {
        float acc = b1[0];
        const __half* xp = X + (size_t)n * 32;
#pragma unroll
        for (int c = 0; c < 8; c++) {
            float4 v = ld_h4(xp + c * 4);
            acc += v.x * W1[c * 4 + 0] + v.y * W1[c * 4 + 1] +
                   v.z * W1[c * 4 + 2] + v.w * W1[c * 4 + 3];
        }
        out[n] = acc;
    }
}

extern "C" void kernel_launch(void* const* d_in, const int* in_sizes, int n_in,
                              void* d_out, int out_size, void* d_ws, size_t ws_size,
                              hipStream_t stream) {
    const float* x    = (const float*)d_in[0];
    const int*   ei   = (const int*)d_in[1];
    const float* W0   = (const float*)d_in[2];
    const float* b0   = (const float*)d_in[3];
    const float* c11W = (const float*)d_in[4];
    const float* c11b = (const float*)d_in[5];
    const float* c12W = (const float*)d_in[6];
    const float* c12b = (const float*)d_in[7];
    const float* c21W = (const float*)d_in[8];
    const float* c21b = (const float*)d_in[9];
    const float* c22W = (const float*)d_in[10];
    const float* c22b = (const float*)d_in[11];
    const float* W1   = (const float*)d_in[12];
    const float* b1   = (const float*)d_in[13];
    float* out = (float*)d_out;

    char* ws = (char*)d_ws;
    int* dsrc = (int*)ws;    ws += (size_t)NN * 4;
    int* ddst = (int*)ws;    ws += (size_t)NN * 4;
    int* cnt  = (int*)ws;    ws += (size_t)NN * 4;   // memset target
    float* dinv = (float*)ws; ws += (size_t)NN * 4;
    int* rowptr = (int*)ws;  ws += (size_t)(NN + 1) * 4;
    int* bsum  = (int*)ws;   ws += 256 * 4;
    int* boff  = (int*)ws;   ws += 256 * 4;
    int2* csr  = (int2*)(((uintptr_t)ws + 15) & ~(uintptr_t)15); ws = (char*)csr + (size_t)EE * 8;
    int* partial = (int*)ws; ws += (size_t)HG * HBK * HB * 4;   // 21.3 MB
    __half* F0 = (__half*)ws; ws += (size_t)NN * HID * 2;
    __half* F1 = (__half*)ws; ws += (size_t)NN * HID * 2;
    __half* P1 = (__half*)ws; ws += (size_t)NN * HID * 2;
    __half* P2 = (__half*)ws; ws += (size_t)NN * HID * 2;

    hipMemsetAsync(cnt, 0, (size_t)NN * 4, stream);

    k_hist<<<HG * HBK, 256, 0, stream>>>(ei, partial);                 // src degrees
    k_hreduce<<<(NN + 255) / 256, 256, 0, stream>>>(partial, dsrc);
    k_hist<<<HG * HBK, 256, 0, stream>>>(ei + EE, partial);            // dst degrees
    k_hreduce<<<(NN + 255) / 256, 256, 0, stream>>>(partial, ddst);
    k_dinv<<<(NN + 255) / 256, 256, 0, stream>>>(dsrc, dinv);
    k_scan1<<<NB, 256, 0, stream>>>(ddst, rowptr, bsum);
    k_scan2<<<1, 256, 0, stream>>>(bsum, boff);
    k_scan3<<<NB, 256, 0, stream>>>(rowptr, boff);
    k_fill<<<(EE + 255) / 256, 256, 0, stream>>>(ei, dinv, rowptr, cnt, csr);

    k_mlp0<<<NN * HID / 256, 256, 0, stream>>>(x, W0, b0, F0);

    auto conv = [&](const __half* T0, const __half* res, __half* outb,
                    const float* W, const float* b, int relu, int has_res) {
        k_prop_csr<<<NN * 8 / 256, 256, 0, stream>>>(rowptr, csr, T0, P1);
        k_prop_csr<<<NN * 8 / 256, 256, 0, stream>>>(rowptr, csr, P1, P2);
        k_cheb<<<NN / 8, 256, 0, stream>>>(T0, P1, P2, res, outb, W, b, relu, has_res);
    };

    conv(F0, nullptr, F1, c11W, c11b, 1, 0);   // block1 conv1: relu
    conv(F1, F0,      F0, c12W, c12b, 1, 1);   // block1 conv2: +res, relu
    conv(F0, nullptr, F1, c21W, c21b, 1, 0);   // block2 conv1: relu
    conv(F1, F0,      F0, c22W, c22b, 1, 1);   // block2 conv2: +res, relu

    k_final<<<(NN + 255) / 256, 256, 0, stream>>>(F0, W1, b1, out);
}